// Round 14
// baseline (1373.039 us; speedup 1.0000x reference)
//
#include <hip/hip_runtime.h>
#include <hip/hip_bf16.h>
#include <stdint.h>

// BitLinear: out = x @ (sign(W)*(|W|>0.7*mean|W|)*scale)^T
// M=16384 (8*2048), K=4096, N=16384. All f32 in/out.
// Round 14: r13 i8 GEMM with 2 LDS buffers (64 KiB) -> TWO blocks/CU.
// Mechanism (m114): independent sync domains overlap matrix & LDS pipes at the
// CU level; block A's read/drain phase hides under block B's MFMA phase.
// Intra-block read-ahead removed (impossible with dbuf=2); per tile:
// {STAGE(t+1) -> reads(t) -> MFMA(t) -> vmcnt(0) -> barrier}. All geometry
// (staging swizzle, read swizzle, cluster map, accumulation order) identical
// to r13 -> absmax unchanged (3.34).

typedef __attribute__((ext_vector_type(4))) int i32x4;

#define M_ROWS 16384
#define K_DIM  4096
#define N_DIM  16384

#define RED_BLOCKS 2048

// ---------- kernel 1a: per-block partial sums of |W| (deterministic) ----------
__global__ void absum_part_kernel(const float4* __restrict__ W4,
                                  double* __restrict__ part, long long n4) {
  double s = 0.0;
  const long long stride = (long long)gridDim.x * blockDim.x;
  for (long long i = (long long)blockIdx.x * blockDim.x + threadIdx.x; i < n4; i += stride) {
    float4 v = W4[i];
    s += (double)fabsf(v.x);
    s += (double)fabsf(v.y);
    s += (double)fabsf(v.z);
    s += (double)fabsf(v.w);
  }
  for (int o = 32; o > 0; o >>= 1) s += __shfl_down(s, o, 64);
  __shared__ double p[4];
  if ((threadIdx.x & 63) == 0) p[threadIdx.x >> 6] = s;
  __syncthreads();
  if (threadIdx.x == 0) part[blockIdx.x] = p[0] + p[1] + p[2] + p[3];
}

// ---------- kernel 1b: reduce partials -> total sum ----------
__global__ void reduce_sum_kernel(const double* __restrict__ part,
                                  double* __restrict__ sum, int n) {
  double s = 0.0;
  for (int i = threadIdx.x; i < n; i += blockDim.x) s += part[i];
  for (int o = 32; o > 0; o >>= 1) s += __shfl_down(s, o, 64);
  __shared__ double p[4];
  if ((threadIdx.x & 63) == 0) p[threadIdx.x >> 6] = s;
  __syncthreads();
  if (threadIdx.x == 0) *sum = p[0] + p[1] + p[2] + p[3];
}

// ---------- kernel 2: ternary-quantize W -> i8 {-1,0,1} [N][K] ----------
__device__ __forceinline__ int tern_i8(float w, float thr) {
  return ((fabsf(w) > thr) ? ((w > 0.0f) ? 1 : -1) : 0) & 255;
}

__global__ void quant_w_kernel(const float4* __restrict__ W4,
                               signed char* __restrict__ Wq,
                               const double* __restrict__ sum_ptr, long long n16) {
  const double mean = *sum_ptr / (double)((long long)N_DIM * K_DIM);
  const float thr = (float)(0.7 * mean);
  const long long stride = (long long)gridDim.x * blockDim.x;
  for (long long i = (long long)blockIdx.x * blockDim.x + threadIdx.x; i < n16; i += stride) {
    float4 a = W4[4 * i], b = W4[4 * i + 1], c = W4[4 * i + 2], d = W4[4 * i + 3];
    int4 o;
    o.x = tern_i8(a.x, thr) | (tern_i8(a.y, thr) << 8) |
          (tern_i8(a.z, thr) << 16) | (tern_i8(a.w, thr) << 24);
    o.y = tern_i8(b.x, thr) | (tern_i8(b.y, thr) << 8) |
          (tern_i8(b.z, thr) << 16) | (tern_i8(b.w, thr) << 24);
    o.z = tern_i8(c.x, thr) | (tern_i8(c.y, thr) << 8) |
          (tern_i8(c.z, thr) << 16) | (tern_i8(c.w, thr) << 24);
    o.w = tern_i8(d.x, thr) | (tern_i8(d.y, thr) << 8) |
          (tern_i8(d.z, thr) << 16) | (tern_i8(d.w, thr) << 24);
    *(int4*)(Wq + i * 16) = o;
  }
}

// ---------- kernel 3: x f32 -> per-row symmetric i8 + scale ----------
__global__ void quant_x_kernel(const float4* __restrict__ X4,
                               signed char* __restrict__ Xq,
                               float* __restrict__ xs) {
  const int row = blockIdx.x;
  const int t = threadIdx.x;
  const float4* src = X4 + (size_t)row * (K_DIM / 4);
  float4 v[4];
#pragma unroll
  for (int i = 0; i < 4; ++i) v[i] = src[i * 256 + t];
  float m = 0.f;
#pragma unroll
  for (int i = 0; i < 4; ++i) {
    m = fmaxf(m, fabsf(v[i].x)); m = fmaxf(m, fabsf(v[i].y));
    m = fmaxf(m, fabsf(v[i].z)); m = fmaxf(m, fabsf(v[i].w));
  }
  for (int o = 32; o > 0; o >>= 1) m = fmaxf(m, __shfl_down(m, o, 64));
  __shared__ float p[4];
  if ((t & 63) == 0) p[t >> 6] = m;
  __syncthreads();
  const float bm = fmaxf(fmaxf(p[0], p[1]), fmaxf(p[2], p[3]));
  const float inv = (bm > 0.f) ? 127.0f / bm : 0.f;
  if (t == 0) xs[row] = (bm > 0.f) ? bm / 127.0f : 0.f;
  int* dst = (int*)(Xq + (size_t)row * K_DIM);
#pragma unroll
  for (int i = 0; i < 4; ++i) {
    const int q0 = __float2int_rn(v[i].x * inv) & 255;
    const int q1 = __float2int_rn(v[i].y * inv) & 255;
    const int q2 = __float2int_rn(v[i].z * inv) & 255;
    const int q3 = __float2int_rn(v[i].w * inv) & 255;
    dst[i * 256 + t] = q0 | (q1 << 8) | (q2 << 16) | (q3 << 24);
  }
}

// ---------- kernel 4: i8 GEMM, 256x256, BK=64B, dbuf=2, 2 blocks/CU ----------
#define BM 256
#define BN 256
#define BK 64
#define NT (K_DIM / BK)   // 64

__global__ __launch_bounds__(512, 2) void gemm_bt_kernel(
    const signed char* __restrict__ A,   // [M][K] i8 (quantized x)
    const signed char* __restrict__ B,   // [N][K] i8 ternary
    float* __restrict__ C,               // [M][N] f32
    const float* __restrict__ xs,        // [M] row scales
    const float* __restrict__ scale_ptr) {
  constexpr int K = K_DIM, N = N_DIM;
  // 2 buffers x {A,B} x 256 rows x 64 bytes = 64 KiB -> 2 blocks/CU
  __shared__ __align__(16) signed char lds[2][2][BM][BK];

  const int tid = threadIdx.x;
  const int wave = tid >> 6;      // 0..7
  const int lane = tid & 63;

  // 2D-clustered XCD map (r7-validated: minimal FETCH)
  const int x = blockIdx.x & 7;   // XCD
  const int l = blockIdx.x >> 3;  // 0..511 within XCD
  const int g = l >> 5;           // round 0..15
  const int s = l & 31;           // position in 4x8 rectangle
  const int bm = g * 4 + (s & 3); // 0..63
  const int bn = x * 8 + (s >> 2);// 0..63

  const int wr = wave >> 2;       // 0..1  (128 rows each)
  const int wc = wave & 3;        // 0..3  (64 cols each)

  const signed char* Ag = A + (size_t)(bm * BM) * K;
  const signed char* Bg = B + (size_t)(bn * BN) * K;

  // staging: chunk = 16 rows x 64B; LDS dest linear; bank swizzle applied
  // inverse at the global source (rule 21). Geometry identical to r13.
  const int strow = lane >> 2;                               // row in chunk 0..15
  const int scol = ((((lane & 3) - (lane >> 3)) & 3) << 4);  // src col in BYTES

  // fragment read (validated 0 conflicts): row = base16 + (lane&15);
  // 16B slot' = ((lane>>4) + (row>>1)) & 3
  const int frow = lane & 15;
  const int fsw = ((((lane >> 4) + ((lane & 15) >> 1)) & 3) << 4);  // bytes

#define STAGE(u, bi)                                                                 \
  {                                                                                  \
    const int kk0_ = (u) * BK;                                                       \
    signed char* Ab_ = &lds[bi][0][0][0];                                            \
    signed char* Bb_ = &lds[bi][1][0][0];                                            \
    _Pragma("unroll")                                                                \
    for (int i_ = 0; i_ < 2; ++i_) {                                                 \
      const int ch_ = wave * 2 + i_;                                                 \
      const int row_ = ch_ * 16 + strow;                                             \
      __builtin_amdgcn_global_load_lds(                                              \
          (__attribute__((address_space(1))) void*)(Ag + (size_t)row_ * K + kk0_ + scol), \
          (__attribute__((address_space(3))) void*)(Ab_ + ch_ * 16 * BK), 16, 0, 0); \
      __builtin_amdgcn_global_load_lds(                                              \
          (__attribute__((address_space(1))) void*)(Bg + (size_t)row_ * K + kk0_ + scol), \
          (__attribute__((address_space(3))) void*)(Bb_ + ch_ * 16 * BK), 16, 0, 0); \
    }                                                                                \
  }

#define RD_B(bi, n_) \
  (*(const i32x4*)(&lds[bi][1][wc * 64 + (n_) * 16 + frow][0] + fsw))
#define RD_A(bi, m_) \
  (*(const i32x4*)(&lds[bi][0][wr * 128 + (m_) * 16 + frow][0] + fsw))

#define SB __builtin_amdgcn_sched_barrier(0)

  // iter: STAGE(t+1 -> other buf); read frags(t); MFMA(t) (compiler pipelines
  // counted lgkm waits per consuming group); vmcnt(0)+barrier at tile end.
  // The drain is covered by the sibling block on the same CU (m114 mechanism).
#define ITER(T, BI)                                                                  \
  {                                                                                  \
    if ((T) + 1 < NT) STAGE((T) + 1, BI ^ 1);                                        \
    SB;                                                                              \
    i32x4 af[8], bf[4];                                                              \
    _Pragma("unroll")                                                                \
    for (int n_ = 0; n_ < 4; ++n_) bf[n_] = RD_B(BI, n_);                            \
    _Pragma("unroll")                                                                \
    for (int m_ = 0; m_ < 8; ++m_) af[m_] = RD_A(BI, m_);                            \
    __builtin_amdgcn_s_setprio(1);                                                   \
    _Pragma("unroll")                                                                \
    for (int m_ = 0; m_ < 8; ++m_)                                                   \
      _Pragma("unroll")                                                              \
      for (int n_ = 0; n_ < 4; ++n_)                                                 \
        acc[m_][n_] = __builtin_amdgcn_mfma_i32_16x16x64_i8(af[m_], bf[n_],          \
                                                            acc[m_][n_], 0, 0, 0);   \
    __builtin_amdgcn_s_setprio(0);                                                   \
    SB;                                                                              \
    if ((T) + 1 < NT) {                                                              \
      asm volatile("s_waitcnt vmcnt(0)" ::: "memory");                               \
      __builtin_amdgcn_s_barrier();                                                  \
    }                                                                                \
    SB;                                                                              \
  }

  i32x4 acc[8][4] = {};

  // ---------- prologue: stage tile 0 into buf 0 ----------
  STAGE(0, 0);
  asm volatile("s_waitcnt vmcnt(0)" ::: "memory");
  __builtin_amdgcn_s_barrier();
  SB;

  for (int t = 0; t < NT; t += 2) {
    ITER(t, 0);
    ITER(t + 1, 1);
  }
#undef ITER
#undef SB
#undef RD_A
#undef RD_B
#undef STAGE

  // ---------------- epilogue: dequantize ----------------
  const float wscale = *scale_ptr;
  const int crow0 = bm * BM + wr * 128;
  const int ccol0 = bn * BN + wc * 64;
#pragma unroll
  for (int m = 0; m < 8; ++m)
#pragma unroll
    for (int j = 0; j < 4; ++j) {
      // C/D layout (m89-verified, dtype-independent): col=lane&15, row=(lane>>4)*4+j
      const int row = crow0 + m * 16 + ((lane >> 4) << 2) + j;
      const float sc = xs[row] * wscale;
#pragma unroll
      for (int n = 0; n < 4; ++n) {
        const int col = ccol0 + n * 16 + (lane & 15);
        C[(size_t)row * N + col] = (float)acc[m][n][j] * sc;
      }
    }
}

extern "C" void kernel_launch(void* const* d_in, const int* in_sizes, int n_in,
                              void* d_out, int out_size, void* d_ws, size_t ws_size,
                              hipStream_t stream) {
  (void)in_sizes; (void)n_in; (void)out_size; (void)ws_size;
  const float* x = (const float*)d_in[0];
  const float* w = (const float*)d_in[1];
  const float* scale = (const float*)d_in[2];
  float* out = (float*)d_out;

  // workspace: part[2048]d @0 | sum d @16384 | xs[16384]f @32768
  //            Wq i8 (64MB) @98304 | Xq i8 (64MB) @98304+64MB
  char* ws = (char*)d_ws;
  double* part = (double*)ws;
  double* sum = (double*)(ws + 16384);
  float* xs = (float*)(ws + 32768);
  signed char* Wq = (signed char*)(ws + 98304);
  signed char* Xq = (signed char*)(ws + 98304 + (size_t)N_DIM * K_DIM);

  const long long nW = (long long)N_DIM * K_DIM;   // 67108864

  absum_part_kernel<<<RED_BLOCKS, 256, 0, stream>>>((const float4*)w, part, nW / 4);
  reduce_sum_kernel<<<1, 256, 0, stream>>>(part, sum, RED_BLOCKS);
  quant_w_kernel<<<2048, 256, 0, stream>>>((const float4*)w, Wq, sum, nW / 16);
  quant_x_kernel<<<M_ROWS, 256, 0, stream>>>((const float4*)x, Xq, xs);

  const int nblocks = (M_ROWS / BM) * (N_DIM / BN);  // 4096
  gemm_bt_kernel<<<nblocks, 512, 0, stream>>>(Xq, Wq, out, xs, scale);
}